// Round 17
// baseline (117.018 us; speedup 1.0000x reference)
//
#include <hip/hip_runtime.h>

#define N_NODES 50000
#define N_EDGES 600000
#define DIN 128
#define HD 128
#define DOUT 64
#define NBINS 196      // 256 nodes per bin
#define BUFCAP 32
#define MAXBIN 6144    // fixed per-bin gbuf region (mean 3061, ~55 sigma headroom)

typedef float f32x4 __attribute__((ext_vector_type(4)));
typedef short bf16x8 __attribute__((ext_vector_type(8)));

__device__ __forceinline__ unsigned short f2bf(float f) {
    unsigned u = __float_as_uint(f);
    unsigned r = (u + 0x7FFFu + ((u >> 16) & 1u)) >> 16;
    return (unsigned short)r;
}

// ---------------- cursor init (must precede mega's scatter blocks) ------------
__global__ __launch_bounds__(256) void cursorinit_kernel(int* __restrict__ binCursor) {
    if (threadIdx.x < NBINS) binCursor[threadIdx.x] = threadIdx.x * MAXBIN;
}

// ---------------- mega: binscatter (256 blk) | xcvt (6250) | bprep (192) ------
// entry = (dst&255)<<17 | src   (src < 50000 < 2^17)
__global__ __launch_bounds__(256) void mega_kernel(const int* __restrict__ ei,
                                                   int* __restrict__ binCursor,
                                                   unsigned* __restrict__ gbuf,
                                                   const float* __restrict__ x,
                                                   unsigned short* __restrict__ xb,
                                                   const float* __restrict__ w1l,
                                                   const float* __restrict__ w1r,
                                                   const float* __restrict__ w2l,
                                                   const float* __restrict__ w2r,
                                                   unsigned short* __restrict__ bfr) {
    int gid = blockIdx.x;
    if (gid < 256) {                     // ---- binned scatter, fixed regions ----
        __shared__ unsigned buf[NBINS][BUFCAP];
        __shared__ int cnt[NBINS];
        for (int i = threadIdx.x; i < NBINS; i += 256) cnt[i] = 0;
        __syncthreads();
        const int per = (N_EDGES + 255) / 256;
        int beg = gid * per;
        int end = min(beg + per, N_EDGES);
        for (int base = beg; base < end; base += 256) {
            int e = base + threadIdx.x;
            if (e < end) {
                int s = ei[e];
                int d = ei[N_EDGES + e];
                int bin = d >> 8;
                unsigned entry = ((unsigned)(d & 255) << 17) | (unsigned)s;
                int pos = atomicAdd(&cnt[bin], 1);
                if (pos < BUFCAP) buf[bin][pos] = entry;
                else { int g = atomicAdd(&binCursor[bin], 1); gbuf[g] = entry; }
            }
            __syncthreads();
            if (threadIdx.x < NBINS) {   // flush full 16-entry (64B) lines
                int b = threadIdx.x;
                int n = cnt[b]; if (n > BUFCAP) n = BUFCAP;
                int k = n & ~15;
                if (k > 0) {
                    int g = atomicAdd(&binCursor[b], k);
                    for (int j = 0; j < k; j++) gbuf[g + j] = buf[b][j];
                    for (int j = 0; j < n - k; j++) buf[b][j] = buf[b][k + j];
                    cnt[b] = n - k;
                } else {
                    cnt[b] = n;
                }
            }
            __syncthreads();
        }
        if (threadIdx.x < NBINS) {       // final partial flush
            int b = threadIdx.x;
            int n = cnt[b]; if (n > BUFCAP) n = BUFCAP;
            if (n > 0) {
                int g = atomicAdd(&binCursor[b], n);
                for (int j = 0; j < n; j++) gbuf[g + j] = buf[b][j];
            }
        }
    } else if (gid < 6506) {             // ---- x -> bf16 (exact 6250 blocks) ----
        int i = (gid - 256) * 256 + threadIdx.x;
        float4 v = ((const float4*)x)[i];
        ushort4 o;
        o.x = f2bf(v.x); o.y = f2bf(v.y); o.z = f2bf(v.z); o.w = f2bf(v.w);
        ((ushort4*)xb)[i] = o;
    } else {                             // ---- weight fragment prep (192) ----
        int tid = (gid - 6506) * 256 + threadIdx.x;  // < 3*16384
        int a = tid >> 14;
        int r = tid & 16383;
        int j = r & 7, lane = (r >> 3) & 63, kc = (r >> 9) & 3, ct = r >> 11;
        int k = kc * 32 + ((lane >> 4) << 3) + j;
        int c = (ct << 4) + (lane & 15);
        float v;
        if (a == 0) v = w1l[k * HD + c];
        else if (a == 1) v = w1r[k * HD + c];
        else v = (c < 64) ? w2l[k * DOUT + c] : w2r[k * DOUT + (c - 64)];
        bfr[tid] = f2bf(v);
    }
}

// ---------------- per-bin sort: row_ptr/row_end + in-place sorted csr ---------
__global__ __launch_bounds__(256) void binsort_kernel(unsigned* __restrict__ gbuf,
                                                      const int* __restrict__ binCursor,
                                                      int* __restrict__ row_ptr,
                                                      int* __restrict__ row_end) {
    __shared__ unsigned ebuf[MAXBIN];
    __shared__ int hist[256];
    __shared__ int cur[256];
    __shared__ int ws[4];
    const int bin = blockIdx.x;
    const int base = bin * MAXBIN;
    int n = binCursor[bin] - base;
    if (n > MAXBIN) n = MAXBIN;
    unsigned* src = gbuf + base;
    for (int i = threadIdx.x; i < n; i += 256) ebuf[i] = src[i];
    hist[threadIdx.x] = 0;
    __syncthreads();
    for (int i = threadIdx.x; i < n; i += 256) atomicAdd(&hist[ebuf[i] >> 17], 1);
    __syncthreads();
    const int lane = threadIdx.x & 63, wid = threadIdx.x >> 6;
    int v = hist[threadIdx.x];
    int incl = v;
#pragma unroll
    for (int off = 1; off < 64; off <<= 1) {
        int t = __shfl_up(incl, (unsigned)off, 64);
        if (lane >= off) incl += t;
    }
    if (lane == 63) ws[wid] = incl;
    __syncthreads();
    int woff = 0;
    for (int w = 0; w < wid; w++) woff += ws[w];
    int excl = woff + incl - v;
    cur[threadIdx.x] = excl;
    int node = bin * 256 + threadIdx.x;
    if (node < N_NODES) {
        row_ptr[node] = base + excl;
        row_end[node] = base + excl + v;
    }
    __syncthreads();
    // in-place scatter: all reads staged in ebuf, safe to overwrite src region
    for (int i = threadIdx.x; i < n; i += 256) {
        unsigned e = ebuf[i];
        int pos = atomicAdd(&cur[e >> 17], 1);
        src[pos] = e & 0x1FFFFu;
    }
}

// ---------------- gather layer-1: 4 slots x 3 predicated parallel loads -------
__global__ __launch_bounds__(256) void gather1_kernel(const int* __restrict__ row_ptr,
                                                      const int* __restrict__ row_end,
                                                      const int* __restrict__ csr,
                                                      const unsigned short* __restrict__ xb,
                                                      unsigned short* __restrict__ meanb) {
    int node = blockIdx.x * 4 + (threadIdx.x >> 6);
    if (node >= N_NODES) return;
    const int lane = threadIdx.x & 63;
    const int g = lane >> 4;   // edge slot 0..3
    const int sl = lane & 15;  // dims [8*sl, 8*sl+8)
    int beg = row_ptr[node], end = row_end[node];
    float acc[8] = {0.f, 0.f, 0.f, 0.f, 0.f, 0.f, 0.f, 0.f};
    for (int base = beg + g; base < end; base += 12) {
        int i1 = base + 4, i2 = base + 8;
        int s0 = csr[base];
        int s1 = csr[i1 < end ? i1 : base];
        int s2 = csr[i2 < end ? i2 : base];
        uint4 u0 = *(const uint4*)(xb + (size_t)s0 * DIN + sl * 8);
        uint4 u1 = *(const uint4*)(xb + (size_t)s1 * DIN + sl * 8);
        uint4 u2 = *(const uint4*)(xb + (size_t)s2 * DIN + sl * 8);
        if (i1 >= end) u1 = (uint4){0u, 0u, 0u, 0u};
        if (i2 >= end) u2 = (uint4){0u, 0u, 0u, 0u};
        acc[0] += __uint_as_float(u0.x << 16) + __uint_as_float(u1.x << 16) + __uint_as_float(u2.x << 16);
        acc[1] += __uint_as_float(u0.x & 0xffff0000u) + __uint_as_float(u1.x & 0xffff0000u) + __uint_as_float(u2.x & 0xffff0000u);
        acc[2] += __uint_as_float(u0.y << 16) + __uint_as_float(u1.y << 16) + __uint_as_float(u2.y << 16);
        acc[3] += __uint_as_float(u0.y & 0xffff0000u) + __uint_as_float(u1.y & 0xffff0000u) + __uint_as_float(u2.y & 0xffff0000u);
        acc[4] += __uint_as_float(u0.z << 16) + __uint_as_float(u1.z << 16) + __uint_as_float(u2.z << 16);
        acc[5] += __uint_as_float(u0.z & 0xffff0000u) + __uint_as_float(u1.z & 0xffff0000u) + __uint_as_float(u2.z & 0xffff0000u);
        acc[6] += __uint_as_float(u0.w << 16) + __uint_as_float(u1.w << 16) + __uint_as_float(u2.w << 16);
        acc[7] += __uint_as_float(u0.w & 0xffff0000u) + __uint_as_float(u1.w & 0xffff0000u) + __uint_as_float(u2.w & 0xffff0000u);
    }
#pragma unroll
    for (int i = 0; i < 8; i++) {
        acc[i] += __shfl_xor(acc[i], 16, 64);
        acc[i] += __shfl_xor(acc[i], 32, 64);
    }
    float r0, r1;
    if (g == 0)      { r0 = acc[0]; r1 = acc[1]; }
    else if (g == 1) { r0 = acc[2]; r1 = acc[3]; }
    else if (g == 2) { r0 = acc[4]; r1 = acc[5]; }
    else             { r0 = acc[6]; r1 = acc[7]; }
    float invd = 1.0f / fmaxf((float)(end - beg), 1.0f);
    ushort2 r; r.x = f2bf(r0 * invd); r.y = f2bf(r1 * invd);
    *(ushort2*)(meanb + (size_t)node * DIN + sl * 8 + g * 2) = r;
}

// ---------------- fused MFMA, 512 thr, B staged in LDS (reg-prefetch 1 ahead) -
// bf16 A-path; h=relu(meanb@w1l + xb@w1r + b1); p=h@w2l; out=h@w2r+b2
__global__ __launch_bounds__(512) void fused_kernel(
    const unsigned short* __restrict__ meanb, const unsigned short* __restrict__ xb,
    const unsigned short* __restrict__ B1a, const unsigned short* __restrict__ B1b,
    const unsigned short* __restrict__ B2,
    const float* __restrict__ b1, const float* __restrict__ b2,
    unsigned short* __restrict__ pb, float* __restrict__ out) {
    __shared__ unsigned short Am[64 * 128];   // 16 KB
    __shared__ unsigned short Ax[64 * 128];   // 16 KB
    __shared__ uint4 Bs[2048];                // 32 KB, current phase's B frags
    const int block0 = blockIdx.x * 64;
    const int tid = threadIdx.x;
    const int lane = tid & 63;
    const int w = tid >> 6;       // 0..7
    const int wtile = w >> 1;     // row tile 0..3 (16 rows each)
    const int chalf = w & 1;      // ct half: 0 -> ct 0..3 (pb), 1 -> ct 4..7 (out)

    // A-tile loads: 1024 uint4 per tile, 512 threads x 2
    uint4 mv[2], xv[2];
#pragma unroll
    for (int i = 0; i < 2; i++) {
        int f = tid + i * 512;
        int row = f >> 4;
        int c8 = f & 15;
        int rg = block0 + row;
        if (rg >= N_NODES) rg = N_NODES - 1;
        mv[i] = *(const uint4*)(meanb + (size_t)rg * DIN + c8 * 8);
        xv[i] = *(const uint4*)(xb + (size_t)rg * DIN + c8 * 8);
    }
    // B1a prefetch into regs (2048 uint4 / 512 threads = 4 each)
    uint4 rb[4];
#pragma unroll
    for (int i = 0; i < 4; i++) rb[i] = ((const uint4*)B1a)[tid + i * 512];

    f32x4 acc[4];
#pragma unroll
    for (int t = 0; t < 4; t++) acc[t] = (f32x4){0.f, 0.f, 0.f, 0.f};

    // stage A tiles (swizzled: byte ^= (row&7)<<4, 16B granules)
#pragma unroll
    for (int i = 0; i < 2; i++) {
        int f = tid + i * 512;
        int row = f >> 4;
        int c8 = f & 15;
        int byte = row * 256 + ((c8 * 16) ^ ((row & 7) << 4));
        *(uint4*)((char*)Am + byte) = mv[i];
        *(uint4*)((char*)Ax + byte) = xv[i];
    }
    auto writeB = [&]() {
#pragma unroll
        for (int i = 0; i < 4; i++) Bs[tid + i * 512] = rb[i];
    };
    writeB();                        // Bs = B1a

    auto compute = [&](const unsigned short* __restrict__ As) {
        const unsigned short* Bf = (const unsigned short*)Bs;
        const int arow = wtile * 16 + (lane & 15);
        const int swz = (arow & 7) << 4;
#pragma unroll
        for (int kc = 0; kc < 4; kc++) {
            int byte = arow * 256 + ((kc * 64 + ((lane >> 4) << 4)) ^ swz);
            bf16x8 a = *(const bf16x8*)((const char*)As + byte);
#pragma unroll
            for (int t = 0; t < 4; t++) {
                int ct = chalf * 4 + t;
                bf16x8 b = *(const bf16x8*)(Bf + ((((ct << 2) + kc) << 6) + lane) * 8);
                acc[t] = __builtin_amdgcn_mfma_f32_16x16x32_bf16(a, b, acc[t], 0, 0, 0);
            }
        }
    };

    __syncthreads();                 // A tiles + Bs(B1a) ready
#pragma unroll
    for (int i = 0; i < 4; i++) rb[i] = ((const uint4*)B1b)[tid + i * 512];  // prefetch B1b
    compute(Am);                     // mean @ w1l  (B1b loads in flight)
    __syncthreads();                 // all waves done reading Bs(B1a)
    writeB();                        // Bs = B1b
#pragma unroll
    for (int i = 0; i < 4; i++) rb[i] = ((const uint4*)B2)[tid + i * 512];   // prefetch B2
    __syncthreads();                 // Bs(B1b) ready
    compute(Ax);                     // + x @ w1r  (B2 loads in flight)
    __syncthreads();                 // all waves done reading Bs(B1b) AND Am rows

    writeB();                        // Bs = B2
    {   // epilogue 1: h = relu(acc + b1) -> restage bf16 into Am (own rows/cols)
        const int r0 = wtile * 16 + ((lane >> 4) << 2);
#pragma unroll
        for (int t = 0; t < 4; t++) {
            int ct = chalf * 4 + t;
            int col = (ct << 4) + (lane & 15);
            float bv = b1[col];
#pragma unroll
            for (int r = 0; r < 4; r++) {
                float v = fmaxf(acc[t][r] + bv, 0.f);
                int row = r0 + r;
                int byte = row * 256 + ((col * 2) ^ ((row & 7) << 4));
                *(unsigned short*)((char*)Am + byte) = f2bf(v);
            }
            acc[t] = (f32x4){0.f, 0.f, 0.f, 0.f};
        }
    }
    __syncthreads();                 // Bs(B2) + full-K h tile ready
    compute(Am);                     // h @ [w2l | w2r]

    {   // epilogue 2: ct 0-3 -> pb (bf16), ct 4-7 -> out (+b2, f32)
        const int r0 = wtile * 16 + ((lane >> 4) << 2);
#pragma unroll
        for (int t = 0; t < 4; t++) {
            int ct = chalf * 4 + t;
            int col = (ct << 4) + (lane & 15);
#pragma unroll
            for (int r = 0; r < 4; r++) {
                int node = block0 + r0 + r;
                if (node < N_NODES) {
                    if (ct < 4) pb[(size_t)node * DOUT + col] = f2bf(acc[t][r]);
                    else out[(size_t)node * DOUT + (col - 64)] = acc[t][r] + b2[col - 64];
                }
            }
        }
    }
}

// ---------------- gather layer-2: 8 slots x 2 predicated parallel loads -------
__global__ __launch_bounds__(256) void gather2_kernel(const int* __restrict__ row_ptr,
                                                      const int* __restrict__ row_end,
                                                      const int* __restrict__ csr,
                                                      const unsigned short* __restrict__ pb,
                                                      float* __restrict__ out) {
    int node = blockIdx.x * 4 + (threadIdx.x >> 6);
    if (node >= N_NODES) return;
    const int lane = threadIdx.x & 63;
    const int g = lane >> 3;  // edge slot 0..7
    const int sl = lane & 7;  // dims [8*sl, 8*sl+8)
    int beg = row_ptr[node], end = row_end[node];
    float acc[8] = {0.f, 0.f, 0.f, 0.f, 0.f, 0.f, 0.f, 0.f};
    for (int base = beg + g; base < end; base += 16) {
        int i1 = base + 8;
        int s0 = csr[base];
        int s1 = csr[i1 < end ? i1 : base];
        uint4 u0 = *(const uint4*)(pb + (size_t)s0 * DOUT + sl * 8);
        uint4 u1 = *(const uint4*)(pb + (size_t)s1 * DOUT + sl * 8);
        if (i1 >= end) u1 = (uint4){0u, 0u, 0u, 0u};
        acc[0] += __uint_as_float(u0.x << 16) + __uint_as_float(u1.x << 16);
        acc[1] += __uint_as_float(u0.x & 0xffff0000u) + __uint_as_float(u1.x & 0xffff0000u);
        acc[2] += __uint_as_float(u0.y << 16) + __uint_as_float(u1.y << 16);
        acc[3] += __uint_as_float(u0.y & 0xffff0000u) + __uint_as_float(u1.y & 0xffff0000u);
        acc[4] += __uint_as_float(u0.z << 16) + __uint_as_float(u1.z << 16);
        acc[5] += __uint_as_float(u0.z & 0xffff0000u) + __uint_as_float(u1.z & 0xffff0000u);
        acc[6] += __uint_as_float(u0.w << 16) + __uint_as_float(u1.w << 16);
        acc[7] += __uint_as_float(u0.w & 0xffff0000u) + __uint_as_float(u1.w & 0xffff0000u);
    }
#pragma unroll
    for (int i = 0; i < 8; i++) {
        acc[i] += __shfl_xor(acc[i], 8, 64);
        acc[i] += __shfl_xor(acc[i], 16, 64);
        acc[i] += __shfl_xor(acc[i], 32, 64);
    }
    float r;
    if (g == 0)      r = acc[0];
    else if (g == 1) r = acc[1];
    else if (g == 2) r = acc[2];
    else if (g == 3) r = acc[3];
    else if (g == 4) r = acc[4];
    else if (g == 5) r = acc[5];
    else if (g == 6) r = acc[6];
    else             r = acc[7];
    float invd = 1.0f / fmaxf((float)(end - beg), 1.0f);
    int d = sl * 8 + g;
    out[(size_t)node * DOUT + d] += r * invd;
}

extern "C" void kernel_launch(void* const* d_in, const int* in_sizes, int n_in,
                              void* d_out, int out_size, void* d_ws, size_t ws_size,
                              hipStream_t stream) {
    const float* x   = (const float*)d_in[0];
    const int*   ei  = (const int*)d_in[1];
    const float* w1l = (const float*)d_in[2];
    const float* b1  = (const float*)d_in[3];
    const float* w1r = (const float*)d_in[4];
    const float* w2l = (const float*)d_in[5];
    const float* b2  = (const float*)d_in[6];
    const float* w2r = (const float*)d_in[7];
    float* out = (float*)d_out;

    // workspace layout
    int* iw = (int*)d_ws;
    int* binCursor = iw;                        // 196
    int* row_ptr   = iw + 256;                  // 50000
    int* row_end   = iw + 50256;                // 50000
    unsigned* gbuf = (unsigned*)(iw + 100352);  // NBINS*MAXBIN = 1204224 (doubles as csr)
    unsigned short* meanb = (unsigned short*)(iw + 1304576);       // N*128 bf16, 16B aligned
    unsigned short* xb  = meanb + (size_t)N_NODES * DIN;           // N*128 bf16
    unsigned short* pbb = xb + (size_t)N_NODES * DIN;              // N*64 bf16
    unsigned short* bfr = pbb + (size_t)N_NODES * DOUT;            // 3*16384 bf16
    const unsigned short* B1a = bfr;
    const unsigned short* B1b = bfr + 16384;
    const unsigned short* B2  = bfr + 32768;
    // total ws use ~= 37.4 MB

    cursorinit_kernel<<<1, 256, 0, stream>>>(binCursor);
    mega_kernel<<<6698, 256, 0, stream>>>(ei, binCursor, gbuf, x, xb,
                                          w1l, w1r, w2l, w2r, bfr);
    binsort_kernel<<<NBINS, 256, 0, stream>>>(gbuf, binCursor, row_ptr, row_end);

    gather1_kernel<<<(N_NODES + 3) / 4, 256, 0, stream>>>(row_ptr, row_end,
                                                          (const int*)gbuf, xb, meanb);
    fused_kernel<<<(N_NODES + 63) / 64, 512, 0, stream>>>(meanb, xb, B1a, B1b, B2,
                                                          b1, b2, pbb, out);
    gather2_kernel<<<(N_NODES + 3) / 4, 256, 0, stream>>>(row_ptr, row_end,
                                                          (const int*)gbuf, pbb, out);
}

// Round 18
// 104.276 us; speedup vs baseline: 1.1222x; 1.1222x over previous
//
#include <hip/hip_runtime.h>

#define N_NODES 50000
#define N_EDGES 600000
#define DIN 128
#define HD 128
#define DOUT 64
#define NBINS 196      // 256 nodes per bin
#define BUFCAP 32
#define MAXBIN 6144    // fixed per-bin gbuf region (mean 3061, ~55 sigma headroom)

typedef float f32x4 __attribute__((ext_vector_type(4)));
typedef short bf16x8 __attribute__((ext_vector_type(8)));

__device__ __forceinline__ unsigned short f2bf(float f) {
    unsigned u = __float_as_uint(f);
    unsigned r = (u + 0x7FFFu + ((u >> 16) & 1u)) >> 16;
    return (unsigned short)r;
}

// ---------------- cursor init (must precede mega's scatter blocks) ------------
__global__ __launch_bounds__(256) void cursorinit_kernel(int* __restrict__ binCursor) {
    if (threadIdx.x < NBINS) binCursor[threadIdx.x] = threadIdx.x * MAXBIN;
}

// ---------------- mega: binscatter (256 blk) | xcvt (6250) | bprep (192) ------
// entry = (dst&255)<<17 | src   (src < 50000 < 2^17)
__global__ __launch_bounds__(256) void mega_kernel(const int* __restrict__ ei,
                                                   int* __restrict__ binCursor,
                                                   unsigned* __restrict__ gbuf,
                                                   const float* __restrict__ x,
                                                   unsigned short* __restrict__ xb,
                                                   const float* __restrict__ w1l,
                                                   const float* __restrict__ w1r,
                                                   const float* __restrict__ w2l,
                                                   const float* __restrict__ w2r,
                                                   unsigned short* __restrict__ bfr) {
    int gid = blockIdx.x;
    if (gid < 256) {                     // ---- binned scatter, fixed regions ----
        __shared__ unsigned buf[NBINS][BUFCAP];
        __shared__ int cnt[NBINS];
        for (int i = threadIdx.x; i < NBINS; i += 256) cnt[i] = 0;
        __syncthreads();
        const int per = (N_EDGES + 255) / 256;
        int beg = gid * per;
        int end = min(beg + per, N_EDGES);
        for (int base = beg; base < end; base += 256) {
            int e = base + threadIdx.x;
            if (e < end) {
                int s = ei[e];
                int d = ei[N_EDGES + e];
                int bin = d >> 8;
                unsigned entry = ((unsigned)(d & 255) << 17) | (unsigned)s;
                int pos = atomicAdd(&cnt[bin], 1);
                if (pos < BUFCAP) buf[bin][pos] = entry;
                else { int g = atomicAdd(&binCursor[bin], 1); gbuf[g] = entry; }
            }
            __syncthreads();
            if (threadIdx.x < NBINS) {   // flush full 16-entry (64B) lines
                int b = threadIdx.x;
                int n = cnt[b]; if (n > BUFCAP) n = BUFCAP;
                int k = n & ~15;
                if (k > 0) {
                    int g = atomicAdd(&binCursor[b], k);
                    for (int j = 0; j < k; j++) gbuf[g + j] = buf[b][j];
                    for (int j = 0; j < n - k; j++) buf[b][j] = buf[b][k + j];
                    cnt[b] = n - k;
                } else {
                    cnt[b] = n;
                }
            }
            __syncthreads();
        }
        if (threadIdx.x < NBINS) {       // final partial flush
            int b = threadIdx.x;
            int n = cnt[b]; if (n > BUFCAP) n = BUFCAP;
            if (n > 0) {
                int g = atomicAdd(&binCursor[b], n);
                for (int j = 0; j < n; j++) gbuf[g + j] = buf[b][j];
            }
        }
    } else if (gid < 6506) {             // ---- x -> bf16 (exact 6250 blocks) ----
        int i = (gid - 256) * 256 + threadIdx.x;
        float4 v = ((const float4*)x)[i];
        ushort4 o;
        o.x = f2bf(v.x); o.y = f2bf(v.y); o.z = f2bf(v.z); o.w = f2bf(v.w);
        ((ushort4*)xb)[i] = o;
    } else {                             // ---- weight fragment prep (192) ----
        int tid = (gid - 6506) * 256 + threadIdx.x;  // < 3*16384
        int a = tid >> 14;
        int r = tid & 16383;
        int j = r & 7, lane = (r >> 3) & 63, kc = (r >> 9) & 3, ct = r >> 11;
        int k = kc * 32 + ((lane >> 4) << 3) + j;
        int c = (ct << 4) + (lane & 15);
        float v;
        if (a == 0) v = w1l[k * HD + c];
        else if (a == 1) v = w1r[k * HD + c];
        else v = (c < 64) ? w2l[k * DOUT + c] : w2r[k * DOUT + (c - 64)];
        bfr[tid] = f2bf(v);
    }
}

// ---------------- per-bin sort: row_ptr/row_end + in-place sorted csr ---------
__global__ __launch_bounds__(256) void binsort_kernel(unsigned* __restrict__ gbuf,
                                                      const int* __restrict__ binCursor,
                                                      int* __restrict__ row_ptr,
                                                      int* __restrict__ row_end) {
    __shared__ unsigned ebuf[MAXBIN];
    __shared__ int hist[256];
    __shared__ int cur[256];
    __shared__ int ws[4];
    const int bin = blockIdx.x;
    const int base = bin * MAXBIN;
    int n = binCursor[bin] - base;
    if (n > MAXBIN) n = MAXBIN;
    unsigned* src = gbuf + base;
    for (int i = threadIdx.x; i < n; i += 256) ebuf[i] = src[i];
    hist[threadIdx.x] = 0;
    __syncthreads();
    for (int i = threadIdx.x; i < n; i += 256) atomicAdd(&hist[ebuf[i] >> 17], 1);
    __syncthreads();
    const int lane = threadIdx.x & 63, wid = threadIdx.x >> 6;
    int v = hist[threadIdx.x];
    int incl = v;
#pragma unroll
    for (int off = 1; off < 64; off <<= 1) {
        int t = __shfl_up(incl, (unsigned)off, 64);
        if (lane >= off) incl += t;
    }
    if (lane == 63) ws[wid] = incl;
    __syncthreads();
    int woff = 0;
    for (int w = 0; w < wid; w++) woff += ws[w];
    int excl = woff + incl - v;
    cur[threadIdx.x] = excl;
    int node = bin * 256 + threadIdx.x;
    if (node < N_NODES) {
        row_ptr[node] = base + excl;
        row_end[node] = base + excl + v;
    }
    __syncthreads();
    // in-place scatter: all reads staged in ebuf, safe to overwrite src region
    for (int i = threadIdx.x; i < n; i += 256) {
        unsigned e = ebuf[i];
        int pos = atomicAdd(&cur[e >> 17], 1);
        src[pos] = e & 0x1FFFFu;
    }
}

// ---------------- gather layer-1: 4 slots x 3 predicated parallel loads -------
__global__ __launch_bounds__(256) void gather1_kernel(const int* __restrict__ row_ptr,
                                                      const int* __restrict__ row_end,
                                                      const int* __restrict__ csr,
                                                      const unsigned short* __restrict__ xb,
                                                      unsigned short* __restrict__ meanb) {
    int node = blockIdx.x * 4 + (threadIdx.x >> 6);
    if (node >= N_NODES) return;
    const int lane = threadIdx.x & 63;
    const int g = lane >> 4;   // edge slot 0..3
    const int sl = lane & 15;  // dims [8*sl, 8*sl+8)
    int beg = row_ptr[node], end = row_end[node];
    float acc[8] = {0.f, 0.f, 0.f, 0.f, 0.f, 0.f, 0.f, 0.f};
    for (int base = beg + g; base < end; base += 12) {
        int i1 = base + 4, i2 = base + 8;
        int s0 = csr[base];
        int s1 = csr[i1 < end ? i1 : base];
        int s2 = csr[i2 < end ? i2 : base];
        uint4 u0 = *(const uint4*)(xb + (size_t)s0 * DIN + sl * 8);
        uint4 u1 = *(const uint4*)(xb + (size_t)s1 * DIN + sl * 8);
        uint4 u2 = *(const uint4*)(xb + (size_t)s2 * DIN + sl * 8);
        if (i1 >= end) u1 = (uint4){0u, 0u, 0u, 0u};
        if (i2 >= end) u2 = (uint4){0u, 0u, 0u, 0u};
        acc[0] += __uint_as_float(u0.x << 16) + __uint_as_float(u1.x << 16) + __uint_as_float(u2.x << 16);
        acc[1] += __uint_as_float(u0.x & 0xffff0000u) + __uint_as_float(u1.x & 0xffff0000u) + __uint_as_float(u2.x & 0xffff0000u);
        acc[2] += __uint_as_float(u0.y << 16) + __uint_as_float(u1.y << 16) + __uint_as_float(u2.y << 16);
        acc[3] += __uint_as_float(u0.y & 0xffff0000u) + __uint_as_float(u1.y & 0xffff0000u) + __uint_as_float(u2.y & 0xffff0000u);
        acc[4] += __uint_as_float(u0.z << 16) + __uint_as_float(u1.z << 16) + __uint_as_float(u2.z << 16);
        acc[5] += __uint_as_float(u0.z & 0xffff0000u) + __uint_as_float(u1.z & 0xffff0000u) + __uint_as_float(u2.z & 0xffff0000u);
        acc[6] += __uint_as_float(u0.w << 16) + __uint_as_float(u1.w << 16) + __uint_as_float(u2.w << 16);
        acc[7] += __uint_as_float(u0.w & 0xffff0000u) + __uint_as_float(u1.w & 0xffff0000u) + __uint_as_float(u2.w & 0xffff0000u);
    }
#pragma unroll
    for (int i = 0; i < 8; i++) {
        acc[i] += __shfl_xor(acc[i], 16, 64);
        acc[i] += __shfl_xor(acc[i], 32, 64);
    }
    float r0, r1;
    if (g == 0)      { r0 = acc[0]; r1 = acc[1]; }
    else if (g == 1) { r0 = acc[2]; r1 = acc[3]; }
    else if (g == 2) { r0 = acc[4]; r1 = acc[5]; }
    else             { r0 = acc[6]; r1 = acc[7]; }
    float invd = 1.0f / fmaxf((float)(end - beg), 1.0f);
    ushort2 r; r.x = f2bf(r0 * invd); r.y = f2bf(r1 * invd);
    *(ushort2*)(meanb + (size_t)node * DIN + sl * 8 + g * 2) = r;
}

// ---------------- fused MFMA, 512 thr / 8 waves: wave = (wtile, ct-half) ------
// bf16 A-path; h=relu(meanb@w1l + xb@w1r + b1); p=h@w2l; out=h@w2r+b2
__global__ __launch_bounds__(512) void fused_kernel(
    const unsigned short* __restrict__ meanb, const unsigned short* __restrict__ xb,
    const unsigned short* __restrict__ B1a, const unsigned short* __restrict__ B1b,
    const unsigned short* __restrict__ B2,
    const float* __restrict__ b1, const float* __restrict__ b2,
    unsigned short* __restrict__ pb, float* __restrict__ out) {
    __shared__ unsigned short Am[64 * 128];   // 16 KB
    __shared__ unsigned short Ax[64 * 128];   // 16 KB
    const int block0 = blockIdx.x * 64;
    const int tid = threadIdx.x;
    const int lane = tid & 63;
    const int w = tid >> 6;       // 0..7
    const int wtile = w >> 1;     // row tile 0..3 (16 rows each)
    const int chalf = w & 1;      // ct half: 0 -> ct 0..3 (pb), 1 -> ct 4..7 (out)

    // A-tile loads: 1024 uint4 per tile, 512 threads x 2
    uint4 mv[2], xv[2];
#pragma unroll
    for (int i = 0; i < 2; i++) {
        int f = tid + i * 512;
        int row = f >> 4;
        int c8 = f & 15;
        int rg = block0 + row;
        if (rg >= N_NODES) rg = N_NODES - 1;
        mv[i] = *(const uint4*)(meanb + (size_t)rg * DIN + c8 * 8);
        xv[i] = *(const uint4*)(xb + (size_t)rg * DIN + c8 * 8);
    }

    f32x4 acc[4];
#pragma unroll
    for (int t = 0; t < 4; t++) acc[t] = (f32x4){0.f, 0.f, 0.f, 0.f};

    // swizzled LDS copy (byte ^= (row&7)<<4, 16B granules)
#pragma unroll
    for (int i = 0; i < 2; i++) {
        int f = tid + i * 512;
        int row = f >> 4;
        int c8 = f & 15;
        int byte = row * 256 + ((c8 * 16) ^ ((row & 7) << 4));
        *(uint4*)((char*)Am + byte) = mv[i];
        *(uint4*)((char*)Ax + byte) = xv[i];
    }

    auto compute = [&](const unsigned short* __restrict__ As,
                       const unsigned short* __restrict__ Bf) {
        const int arow = wtile * 16 + (lane & 15);
        const int swz = (arow & 7) << 4;
#pragma unroll
        for (int kc = 0; kc < 4; kc++) {
            int byte = arow * 256 + ((kc * 64 + ((lane >> 4) << 4)) ^ swz);
            bf16x8 a = *(const bf16x8*)((const char*)As + byte);
#pragma unroll
            for (int t = 0; t < 4; t++) {
                int ct = chalf * 4 + t;
                bf16x8 b = *(const bf16x8*)(Bf + ((((ct << 2) + kc) << 6) + lane) * 8);
                acc[t] = __builtin_amdgcn_mfma_f32_16x16x32_bf16(a, b, acc[t], 0, 0, 0);
            }
        }
    };

    __syncthreads();
    compute(Am, B1a);               // mean @ w1l
    compute(Ax, B1b);               // + x @ w1r
    __syncthreads();                // sibling chalf wave shares Am rows: must finish reads

    {   // epilogue 1: h = relu(acc + b1) -> restage bf16 into Am (disjoint cols)
        const int r0 = wtile * 16 + ((lane >> 4) << 2);
#pragma unroll
        for (int t = 0; t < 4; t++) {
            int ct = chalf * 4 + t;
            int col = (ct << 4) + (lane & 15);
            float bv = b1[col];
#pragma unroll
            for (int r = 0; r < 4; r++) {
                float v = fmaxf(acc[t][r] + bv, 0.f);
                int row = r0 + r;
                int byte = row * 256 + ((col * 2) ^ ((row & 7) << 4));
                *(unsigned short*)((char*)Am + byte) = f2bf(v);
            }
            acc[t] = (f32x4){0.f, 0.f, 0.f, 0.f};
        }
    }
    __syncthreads();                // full-K read below needs sibling's cols
    compute(Am, B2);                // h @ [w2l | w2r]

    {   // epilogue 2: ct 0-3 -> pb (bf16), ct 4-7 -> out (+b2, f32)
        const int r0 = wtile * 16 + ((lane >> 4) << 2);
#pragma unroll
        for (int t = 0; t < 4; t++) {
            int ct = chalf * 4 + t;
            int col = (ct << 4) + (lane & 15);
#pragma unroll
            for (int r = 0; r < 4; r++) {
                int node = block0 + r0 + r;
                if (node < N_NODES) {
                    if (ct < 4) pb[(size_t)node * DOUT + col] = f2bf(acc[t][r]);
                    else out[(size_t)node * DOUT + (col - 64)] = acc[t][r] + b2[col - 64];
                }
            }
        }
    }
}

// ---------------- gather layer-2: 8 slots x 2 predicated parallel loads -------
__global__ __launch_bounds__(256) void gather2_kernel(const int* __restrict__ row_ptr,
                                                      const int* __restrict__ row_end,
                                                      const int* __restrict__ csr,
                                                      const unsigned short* __restrict__ pb,
                                                      float* __restrict__ out) {
    int node = blockIdx.x * 4 + (threadIdx.x >> 6);
    if (node >= N_NODES) return;
    const int lane = threadIdx.x & 63;
    const int g = lane >> 3;  // edge slot 0..7
    const int sl = lane & 7;  // dims [8*sl, 8*sl+8)
    int beg = row_ptr[node], end = row_end[node];
    float acc[8] = {0.f, 0.f, 0.f, 0.f, 0.f, 0.f, 0.f, 0.f};
    for (int base = beg + g; base < end; base += 16) {
        int i1 = base + 8;
        int s0 = csr[base];
        int s1 = csr[i1 < end ? i1 : base];
        uint4 u0 = *(const uint4*)(pb + (size_t)s0 * DOUT + sl * 8);
        uint4 u1 = *(const uint4*)(pb + (size_t)s1 * DOUT + sl * 8);
        if (i1 >= end) u1 = (uint4){0u, 0u, 0u, 0u};
        acc[0] += __uint_as_float(u0.x << 16) + __uint_as_float(u1.x << 16);
        acc[1] += __uint_as_float(u0.x & 0xffff0000u) + __uint_as_float(u1.x & 0xffff0000u);
        acc[2] += __uint_as_float(u0.y << 16) + __uint_as_float(u1.y << 16);
        acc[3] += __uint_as_float(u0.y & 0xffff0000u) + __uint_as_float(u1.y & 0xffff0000u);
        acc[4] += __uint_as_float(u0.z << 16) + __uint_as_float(u1.z << 16);
        acc[5] += __uint_as_float(u0.z & 0xffff0000u) + __uint_as_float(u1.z & 0xffff0000u);
        acc[6] += __uint_as_float(u0.w << 16) + __uint_as_float(u1.w << 16);
        acc[7] += __uint_as_float(u0.w & 0xffff0000u) + __uint_as_float(u1.w & 0xffff0000u);
    }
#pragma unroll
    for (int i = 0; i < 8; i++) {
        acc[i] += __shfl_xor(acc[i], 8, 64);
        acc[i] += __shfl_xor(acc[i], 16, 64);
        acc[i] += __shfl_xor(acc[i], 32, 64);
    }
    float r;
    if (g == 0)      r = acc[0];
    else if (g == 1) r = acc[1];
    else if (g == 2) r = acc[2];
    else if (g == 3) r = acc[3];
    else if (g == 4) r = acc[4];
    else if (g == 5) r = acc[5];
    else if (g == 6) r = acc[6];
    else             r = acc[7];
    float invd = 1.0f / fmaxf((float)(end - beg), 1.0f);
    int d = sl * 8 + g;
    out[(size_t)node * DOUT + d] += r * invd;
}

extern "C" void kernel_launch(void* const* d_in, const int* in_sizes, int n_in,
                              void* d_out, int out_size, void* d_ws, size_t ws_size,
                              hipStream_t stream) {
    const float* x   = (const float*)d_in[0];
    const int*   ei  = (const int*)d_in[1];
    const float* w1l = (const float*)d_in[2];
    const float* b1  = (const float*)d_in[3];
    const float* w1r = (const float*)d_in[4];
    const float* w2l = (const float*)d_in[5];
    const float* b2  = (const float*)d_in[6];
    const float* w2r = (const float*)d_in[7];
    float* out = (float*)d_out;

    // workspace layout
    int* iw = (int*)d_ws;
    int* binCursor = iw;                        // 196
    int* row_ptr   = iw + 256;                  // 50000
    int* row_end   = iw + 50256;                // 50000
    unsigned* gbuf = (unsigned*)(iw + 100352);  // NBINS*MAXBIN = 1204224 (doubles as csr)
    unsigned short* meanb = (unsigned short*)(iw + 1304576);       // N*128 bf16, 16B aligned
    unsigned short* xb  = meanb + (size_t)N_NODES * DIN;           // N*128 bf16
    unsigned short* pbb = xb + (size_t)N_NODES * DIN;              // N*64 bf16
    unsigned short* bfr = pbb + (size_t)N_NODES * DOUT;            // 3*16384 bf16
    const unsigned short* B1a = bfr;
    const unsigned short* B1b = bfr + 16384;
    const unsigned short* B2  = bfr + 32768;
    // total ws use ~= 37.4 MB

    cursorinit_kernel<<<1, 256, 0, stream>>>(binCursor);
    mega_kernel<<<6698, 256, 0, stream>>>(ei, binCursor, gbuf, x, xb,
                                          w1l, w1r, w2l, w2r, bfr);
    binsort_kernel<<<NBINS, 256, 0, stream>>>(gbuf, binCursor, row_ptr, row_end);

    gather1_kernel<<<(N_NODES + 3) / 4, 256, 0, stream>>>(row_ptr, row_end,
                                                          (const int*)gbuf, xb, meanb);
    fused_kernel<<<(N_NODES + 63) / 64, 512, 0, stream>>>(meanb, xb, B1a, B1b, B2,
                                                          b1, b2, pbb, out);
    gather2_kernel<<<(N_NODES + 3) / 4, 256, 0, stream>>>(row_ptr, row_end,
                                                          (const int*)gbuf, pbb, out);
}